// Round 6
// baseline (139.063 us; speedup 1.0000x reference)
//
#include <hip/hip_runtime.h>
#include <hip/hip_bf16.h>

// B=2, N=512, C=256
// score[b,i,j] = sum_c relu(q_ic + k_jc) = 0.5*(Qs_i + Ks_j + sum_c |q_ic + k_jc|)
// Qs_i is row-constant -> cancels in softmax. Kernel uses score' = 0.5*(Sabs_ij + Ks_j).

#define QSTR 132   // q/k LDS stride (dwords): even quad-bank spread for b128
#define VSTR 260   // v LDS stride (dwords)

// ---------------- Kernel 1: fused QKV projection ----------------
// z==0 -> q stored TRANSPOSED as qt4[c4][1024rows]; z==1 -> k row-major + Ksp
// partial row-sums; z==2 -> v row-major.
__global__ __launch_bounds__(256, 2) void gemm_qkv(
    const float* __restrict__ x,
    const float* __restrict__ Wq, const float* __restrict__ Wk, const float* __restrict__ Wv,
    float4* __restrict__ qt4, float* __restrict__ k, float* __restrict__ v,
    float* __restrict__ Ksp)
{
    const int z = blockIdx.z;
    const float* W = (z == 0) ? Wq : ((z == 1) ? Wk : Wv);
    const int row0 = blockIdx.x * 32;
    const int d0   = blockIdx.y * 64;

    __shared__ __attribute__((aligned(16))) float AT[32][36];  // [c][row]
    __shared__ __attribute__((aligned(16))) float WT[32][68];  // [c][d]

    const int tid = threadIdx.x;
    const int ty = tid >> 4, tx = tid & 15;

    float acc[2][4] = {};

    for (int c0 = 0; c0 < 256; c0 += 32) {
        {
            int r  = tid >> 3;
            int cb = (tid & 7) * 4;
            float4 a = *(const float4*)&x[(size_t)(row0 + r) * 256 + c0 + cb];
            AT[cb + 0][r] = a.x; AT[cb + 1][r] = a.y;
            AT[cb + 2][r] = a.z; AT[cb + 3][r] = a.w;
        }
        {
            int d  = tid >> 2;
            int cq = (tid & 3) * 8;
            float4 w0 = *(const float4*)&W[(size_t)(d0 + d) * 256 + c0 + cq];
            float4 w1 = *(const float4*)&W[(size_t)(d0 + d) * 256 + c0 + cq + 4];
            WT[cq + 0][d] = w0.x; WT[cq + 1][d] = w0.y;
            WT[cq + 2][d] = w0.z; WT[cq + 3][d] = w0.w;
            WT[cq + 4][d] = w1.x; WT[cq + 5][d] = w1.y;
            WT[cq + 6][d] = w1.z; WT[cq + 7][d] = w1.w;
        }
        __syncthreads();
#pragma unroll
        for (int c = 0; c < 32; ++c) {
            float2 a  = *(const float2*)&AT[c][ty * 2];
            float4 w4 = *(const float4*)&WT[c][tx * 4];
            acc[0][0] += a.x * w4.x; acc[0][1] += a.x * w4.y;
            acc[0][2] += a.x * w4.z; acc[0][3] += a.x * w4.w;
            acc[1][0] += a.y * w4.x; acc[1][1] += a.y * w4.y;
            acc[1][2] += a.y * w4.z; acc[1][3] += a.y * w4.w;
        }
        __syncthreads();
    }

    if (z == 0) {
#pragma unroll
        for (int rr = 0; rr < 2; ++rr)
            qt4[(size_t)(d0 / 4 + tx) * 1024 + row0 + ty * 2 + rr] =
                make_float4(acc[rr][0], acc[rr][1], acc[rr][2], acc[rr][3]);
    } else {
        float* out = (z == 1) ? k : v;
#pragma unroll
        for (int rr = 0; rr < 2; ++rr)
            *(float4*)&out[(size_t)(row0 + ty * 2 + rr) * 256 + d0 + tx * 4] =
                make_float4(acc[rr][0], acc[rr][1], acc[rr][2], acc[rr][3]);
        if (z == 1) {
#pragma unroll
            for (int rr = 0; rr < 2; ++rr) {
                float kp = acc[rr][0] + acc[rr][1] + acc[rr][2] + acc[rr][3];
#pragma unroll
                for (int d = 1; d < 16; d <<= 1) kp += __shfl_xor(kp, d, 16);
                if (tx == 0)
                    Ksp[(size_t)(d0 >> 6) * 1024 + row0 + ty * 2 + rr] = kp;
            }
        }
    }
}

// ---------------- Kernel 2: attention partial (split-j) ----------------
// 512 thr = 8 waves, lane = query row (64 rows), wave w = j-quad {4w..4w+3}.
// q: per-lane b128 from LDS (stride 132). k,v: LDS wave-uniform BROADCAST b128.
// launch_bounds(512,1): on this toolchain arg2 acts as blocks/CU for 512-thr
// blocks ((512,2)->128 VGPR cap, (512,4)->64, both spilled). 1 block/CU ->
// 256-VGPR cap, no spill; grid=256 blocks=1/CU so no occupancy loss.
__global__ __launch_bounds__(512, 1) void attn_partial(
    const float4* __restrict__ qt4, const float* __restrict__ kk,
    const float* __restrict__ vv, const float* __restrict__ Ksp,
    float* __restrict__ pacc, float* __restrict__ ml)
{
    const int it = blockIdx.x;          // 0..15 : 64-row tile (flat rows b*512+n)
    const int js = blockIdx.y;          // 0..15 : 32-key chunk within batch
    const int b  = it >> 3;
    const int irow0 = it * 64;
    const int jrow0 = b * 512 + js * 32;

    __shared__ __attribute__((aligned(16))) float qbuf[64 * QSTR];  // 33.8 KB; reused for v
    __shared__ __attribute__((aligned(16))) float kbuf[32 * QSTR];  // 16.9 KB
    __shared__ float sL[32][65];
    __shared__ float pl[32][65];

    const int t = threadIdx.x;
    const int w = t >> 6;               // wave 0..7
    const int l = t & 63;               // lane = local query row
    const int j0 = w * 4;

    float s[4] = {0.f, 0.f, 0.f, 0.f};

    for (int h = 0; h < 2; ++h) {
        // stage q half-tile 64x128 from qt4[c4][row] (coalesced)
#pragma unroll
        for (int u = 0; u < 4; ++u) {
            int idx = u * 512 + t;
            int c4 = idx >> 6, row = idx & 63;
            float4 a = qt4[(size_t)(h * 32 + c4) * 1024 + irow0 + row];
            *(float4*)&qbuf[row * QSTR + c4 * 4] = a;
        }
        // stage k half-tile 32x128
#pragma unroll
        for (int u = 0; u < 2; ++u) {
            int idx = u * 512 + t;
            int row = idx >> 5, c4 = idx & 31;
            float4 a = *(const float4*)&kk[(size_t)(jrow0 + row) * 256 + h * 128 + c4 * 4];
            *(float4*)&kbuf[row * QSTR + c4 * 4] = a;
        }
        __syncthreads();

        for (int c0 = 0; c0 < 128; c0 += 8) {
            float4 qa = *(const float4*)&qbuf[l * QSTR + c0];
            float4 qb = *(const float4*)&qbuf[l * QSTR + c0 + 4];
#pragma unroll
            for (int jj = 0; jj < 4; ++jj) {
                float4 ka = *(const float4*)&kbuf[(j0 + jj) * QSTR + c0];      // broadcast
                float4 kb = *(const float4*)&kbuf[(j0 + jj) * QSTR + c0 + 4];  // broadcast
                s[jj] += fabsf(qa.x + ka.x);
                s[jj] += fabsf(qa.y + ka.y);
                s[jj] += fabsf(qa.z + ka.z);
                s[jj] += fabsf(qa.w + ka.w);
                s[jj] += fabsf(qb.x + kb.x);
                s[jj] += fabsf(qb.y + kb.y);
                s[jj] += fabsf(qb.z + kb.z);
                s[jj] += fabsf(qb.w + kb.w);
            }
        }
        __syncthreads();   // before restaging
    }

    // score' = 0.5*(Sabs + Ks_j)  (Ks via 4 precomputed partials, wave-uniform)
    const int jbase = jrow0 + j0;
    float sc[4];
#pragma unroll
    for (int jj = 0; jj < 4; ++jj) {
        float ks = Ksp[jbase + jj] + Ksp[1024 + jbase + jj]
                 + Ksp[2048 + jbase + jj] + Ksp[3072 + jbase + jj];
        sc[jj] = 0.5f * (s[jj] + ks);
        sL[j0 + jj][l] = sc[jj];
    }

    // stage v 32x256 into qbuf (q dead after score; barrier below publishes both)
#pragma unroll
    for (int u = 0; u < 4; ++u) {
        int idx = u * 512 + t;
        int row = idx >> 6, c4 = idx & 63;
        float4 a = *(const float4*)&vv[(size_t)(jrow0 + row) * 256 + c4 * 4];
        *(float4*)&qbuf[row * VSTR + c4 * 4] = a;
    }
    __syncthreads();

    float m = -1e30f;
#pragma unroll
    for (int j = 0; j < 32; ++j) m = fmaxf(m, sL[j][l]);
#pragma unroll
    for (int jj = 0; jj < 4; ++jj)
        pl[j0 + jj][l] = __expf(sc[jj] - m);
    __syncthreads();

    if (w == 0) {
        float lsum = 0.f;
#pragma unroll
        for (int j = 0; j < 32; ++j) lsum += pl[j][l];
        *(float2*)&ml[((size_t)(irow0 + l) * 16 + js) * 2] = make_float2(m, lsum);
    }

    // PV: wave w owns c-slice [32w,32w+32); v broadcast b128, p 1xb32/j, acc[32] regs
    const int cb = w * 32;
    float acc[32];
#pragma unroll
    for (int i = 0; i < 32; ++i) acc[i] = 0.f;
#pragma unroll 2
    for (int j = 0; j < 32; ++j) {
        float pj = pl[j][l];
#pragma unroll
        for (int c4 = 0; c4 < 8; ++c4) {
            float4 vv4 = *(const float4*)&qbuf[j * VSTR + cb + c4 * 4];  // broadcast
            acc[c4 * 4 + 0] += pj * vv4.x;
            acc[c4 * 4 + 1] += pj * vv4.y;
            acc[c4 * 4 + 2] += pj * vv4.z;
            acc[c4 * 4 + 3] += pj * vv4.w;
        }
    }
    float* pb = pacc + (((size_t)it * 16 + js) * 256 + cb) * 64 + l;
#pragma unroll
    for (int cc = 0; cc < 32; ++cc) pb[(size_t)cc * 64] = acc[cc];
}

// ---------------- Kernel 3: combine split-j partials -> O^T [256][1024] ----------------
__global__ __launch_bounds__(256) void combine(
    const float* __restrict__ pacc, const float* __restrict__ ml, float* __restrict__ OT)
{
    const int it = blockIdx.x;   // 0..15
    const int cs = blockIdx.y;   // 0..15 (16-c slice)
    const int t  = threadIdx.x;
    const int il = t & 63, cq = t >> 6;      // cq 0..3
    const int row = it * 64 + il;
    const int c0  = cs * 16 + cq * 4;

    float mv[16], lv[16], M = -1e30f;
#pragma unroll
    for (int s = 0; s < 16; ++s) {
        float2 e = *(const float2*)&ml[((size_t)row * 16 + s) * 2];
        mv[s] = e.x; lv[s] = e.y; M = fmaxf(M, e.x);
    }
    float L = 0.f;
    float o[4] = {0.f, 0.f, 0.f, 0.f};
#pragma unroll
    for (int s = 0; s < 16; ++s) {
        float wgt = __expf(mv[s] - M);
        L += wgt * lv[s];
        const float* pb = pacc + (((size_t)it * 16 + s) * 256 + c0) * 64 + il;
#pragma unroll
        for (int i = 0; i < 4; ++i) o[i] += wgt * pb[(size_t)i * 64];
    }
    float inv = 1.f / L;
#pragma unroll
    for (int i = 0; i < 4; ++i)
        OT[(size_t)(c0 + i) * 1024 + row] = o[i] * inv;
}

// ---------------- Kernel 4: final projection + bias (reads O^T) ----------------
__global__ __launch_bounds__(256, 2) void gemm_bias(
    const float* __restrict__ OT, const float* __restrict__ W,
    const float* __restrict__ bias, float* __restrict__ out)
{
    const int row0 = blockIdx.x * 32;
    const int d0   = blockIdx.y * 64;

    __shared__ __attribute__((aligned(16))) float AT[32][36];
    __shared__ __attribute__((aligned(16))) float WT[32][68];

    const int tid = threadIdx.x;
    const int ty = tid >> 4, tx = tid & 15;

    float acc[2][4] = {};

    for (int c0 = 0; c0 < 256; c0 += 32) {
        {
            int cc = tid >> 3, r = (tid & 7) * 4;
            float4 a = *(const float4*)&OT[(size_t)(c0 + cc) * 1024 + row0 + r];
            *(float4*)&AT[cc][r] = a;
        }
        {
            int d  = tid >> 2;
            int cq = (tid & 3) * 8;
            float4 w0 = *(const float4*)&W[(size_t)(d0 + d) * 256 + c0 + cq];
            float4 w1 = *(const float4*)&W[(size_t)(d0 + d) * 256 + c0 + cq + 4];
            WT[cq + 0][d] = w0.x; WT[cq + 1][d] = w0.y;
            WT[cq + 2][d] = w0.z; WT[cq + 3][d] = w0.w;
            WT[cq + 4][d] = w1.x; WT[cq + 5][d] = w1.y;
            WT[cq + 6][d] = w1.z; WT[cq + 7][d] = w1.w;
        }
        __syncthreads();
#pragma unroll
        for (int c = 0; c < 32; ++c) {
            float2 a  = *(const float2*)&AT[c][ty * 2];
            float4 w4 = *(const float4*)&WT[c][tx * 4];
            acc[0][0] += a.x * w4.x; acc[0][1] += a.x * w4.y;
            acc[0][2] += a.x * w4.z; acc[0][3] += a.x * w4.w;
            acc[1][0] += a.y * w4.x; acc[1][1] += a.y * w4.y;
            acc[1][2] += a.y * w4.z; acc[1][3] += a.y * w4.w;
        }
        __syncthreads();
    }
    float4 bb = *(const float4*)&bias[d0 + tx * 4];
#pragma unroll
    for (int rr = 0; rr < 2; ++rr) {
        float4 o = make_float4(acc[rr][0] + bb.x, acc[rr][1] + bb.y,
                               acc[rr][2] + bb.z, acc[rr][3] + bb.w);
        *(float4*)&out[(size_t)(row0 + ty * 2 + rr) * 256 + d0 + tx * 4] = o;
    }
}

extern "C" void kernel_launch(void* const* d_in, const int* in_sizes, int n_in,
                              void* d_out, int out_size, void* d_ws, size_t ws_size,
                              hipStream_t stream) {
    const float* x  = (const float*)d_in[0];
    const float* Wq = (const float*)d_in[1];
    const float* Wk = (const float*)d_in[2];
    const float* Wv = (const float*)d_in[3];
    const float* Wp = (const float*)d_in[4];
    const float* bp = (const float*)d_in[5];
    float* out = (float*)d_out;
    (void)ws_size; (void)in_sizes; (void)n_in; (void)out_size;

    float* ws = (float*)d_ws;
    const size_t BNC = (size_t)2 * 512 * 256;              // 262144
    float4* qt4 = (float4*)ws;                             // [64 c4][1024] = 1 MB
    float* k    = ws + BNC;
    float* v    = k + BNC;
    float* OT   = v + BNC;                                 // [256][1024]
    float* Ksp  = OT + BNC;                                // [4][1024]
    float* pacc = Ksp + 4 * 1024;                          // [16][16][256][64] = 16.8 MB
    float* mlb  = pacc + (size_t)16 * 16 * 256 * 64;       // [1024][16][2]

    gemm_qkv<<<dim3(32, 4, 3), 256, 0, stream>>>(x, Wq, Wk, Wv, qt4, k, v, Ksp);
    attn_partial<<<dim3(16, 16), 512, 0, stream>>>(qt4, k, v, Ksp, pacc, mlb);
    combine<<<dim3(16, 16), 256, 0, stream>>>(pacc, mlb, OT);
    gemm_bias<<<dim3(32, 4), 256, 0, stream>>>(OT, Wp, bp, out);
}

// Round 7
// 60.642 us; speedup vs baseline: 2.2932x; 2.2932x over previous
//
#include <hip/hip_runtime.h>
#include <hip/hip_bf16.h>

// B=2, N=512, C=256
// score[b,i,j] = sum_c relu(q_ic + k_jc) = 0.5*(Qs_i + Ks_j + sum_c |q_ic + k_jc|)
// Qs_i is row-constant -> cancels in softmax. Kernel uses score' = 0.5*(Sabs_ij + Ks_j).

#define QSTR 132   // q/k LDS stride (dwords): even quad-bank spread for b128
#define VSTR 260   // v LDS stride (dwords)

// ---------------- Kernel 1: fused QKV projection ----------------
// z==0 -> q stored TRANSPOSED as qt4[c4][1024rows]; z==1 -> k row-major + Ksp
// partial row-sums; z==2 -> v row-major.
__global__ __launch_bounds__(256, 2) void gemm_qkv(
    const float* __restrict__ x,
    const float* __restrict__ Wq, const float* __restrict__ Wk, const float* __restrict__ Wv,
    float4* __restrict__ qt4, float* __restrict__ k, float* __restrict__ v,
    float* __restrict__ Ksp)
{
    const int z = blockIdx.z;
    const float* W = (z == 0) ? Wq : ((z == 1) ? Wk : Wv);
    const int row0 = blockIdx.x * 32;
    const int d0   = blockIdx.y * 64;

    __shared__ __attribute__((aligned(16))) float AT[32][36];  // [c][row]
    __shared__ __attribute__((aligned(16))) float WT[32][68];  // [c][d]

    const int tid = threadIdx.x;
    const int ty = tid >> 4, tx = tid & 15;

    float acc[2][4] = {};

    for (int c0 = 0; c0 < 256; c0 += 32) {
        {
            int r  = tid >> 3;
            int cb = (tid & 7) * 4;
            float4 a = *(const float4*)&x[(size_t)(row0 + r) * 256 + c0 + cb];
            AT[cb + 0][r] = a.x; AT[cb + 1][r] = a.y;
            AT[cb + 2][r] = a.z; AT[cb + 3][r] = a.w;
        }
        {
            int d  = tid >> 2;
            int cq = (tid & 3) * 8;
            float4 w0 = *(const float4*)&W[(size_t)(d0 + d) * 256 + c0 + cq];
            float4 w1 = *(const float4*)&W[(size_t)(d0 + d) * 256 + c0 + cq + 4];
            WT[cq + 0][d] = w0.x; WT[cq + 1][d] = w0.y;
            WT[cq + 2][d] = w0.z; WT[cq + 3][d] = w0.w;
            WT[cq + 4][d] = w1.x; WT[cq + 5][d] = w1.y;
            WT[cq + 6][d] = w1.z; WT[cq + 7][d] = w1.w;
        }
        __syncthreads();
#pragma unroll
        for (int c = 0; c < 32; ++c) {
            float2 a  = *(const float2*)&AT[c][ty * 2];
            float4 w4 = *(const float4*)&WT[c][tx * 4];
            acc[0][0] += a.x * w4.x; acc[0][1] += a.x * w4.y;
            acc[0][2] += a.x * w4.z; acc[0][3] += a.x * w4.w;
            acc[1][0] += a.y * w4.x; acc[1][1] += a.y * w4.y;
            acc[1][2] += a.y * w4.z; acc[1][3] += a.y * w4.w;
        }
        __syncthreads();
    }

    if (z == 0) {
#pragma unroll
        for (int rr = 0; rr < 2; ++rr)
            qt4[(size_t)(d0 / 4 + tx) * 1024 + row0 + ty * 2 + rr] =
                make_float4(acc[rr][0], acc[rr][1], acc[rr][2], acc[rr][3]);
    } else {
        float* out = (z == 1) ? k : v;
#pragma unroll
        for (int rr = 0; rr < 2; ++rr)
            *(float4*)&out[(size_t)(row0 + ty * 2 + rr) * 256 + d0 + tx * 4] =
                make_float4(acc[rr][0], acc[rr][1], acc[rr][2], acc[rr][3]);
        if (z == 1) {
#pragma unroll
            for (int rr = 0; rr < 2; ++rr) {
                float kp = acc[rr][0] + acc[rr][1] + acc[rr][2] + acc[rr][3];
#pragma unroll
                for (int d = 1; d < 16; d <<= 1) kp += __shfl_xor(kp, d, 16);
                if (tx == 0)
                    Ksp[(size_t)(d0 >> 6) * 1024 + row0 + ty * 2 + rr] = kp;
            }
        }
    }
}

// ---------------- Kernel 2: attention partial (split-j) ----------------
// 512 thr = 8 waves, lane = query row (64 rows), wave w = j-quad {4w..4w+3}.
// q: per-lane b128 from LDS. k,v: wave-uniform BROADCAST b128 from LDS.
// SPILL CONTROL (R6 evidence: compiler pins 128 VGPR for 512-thr blocks and
// spills ~400 dwords/thread): score c0 loop unroll 1 (full 16x unroll put
// ~640 dwords of ds_read results in flight); PV split into two acc[16] passes.
// Peak live set now ~60 regs, comfortably under the 128 cap.
__global__ __launch_bounds__(512) void attn_partial(
    const float4* __restrict__ qt4, const float* __restrict__ kk,
    const float* __restrict__ vv, const float* __restrict__ Ksp,
    float* __restrict__ pacc, float* __restrict__ ml)
{
    const int it = blockIdx.x;          // 0..15 : 64-row tile (flat rows b*512+n)
    const int js = blockIdx.y;          // 0..15 : 32-key chunk within batch
    const int b  = it >> 3;
    const int irow0 = it * 64;
    const int jrow0 = b * 512 + js * 32;

    __shared__ __attribute__((aligned(16))) float qbuf[64 * QSTR];  // 33.8 KB; reused for v
    __shared__ __attribute__((aligned(16))) float kbuf[32 * QSTR];  // 16.9 KB
    __shared__ float sL[32][65];
    __shared__ float pl[32][65];

    const int t = threadIdx.x;
    const int w = t >> 6;               // wave 0..7
    const int l = t & 63;               // lane = local query row
    const int j0 = w * 4;

    float s[4] = {0.f, 0.f, 0.f, 0.f};

    for (int h = 0; h < 2; ++h) {
        // stage q half-tile 64x128 from qt4[c4][row] (coalesced)
#pragma unroll
        for (int u = 0; u < 4; ++u) {
            int idx = u * 512 + t;
            int c4 = idx >> 6, row = idx & 63;
            float4 a = qt4[(size_t)(h * 32 + c4) * 1024 + irow0 + row];
            *(float4*)&qbuf[row * QSTR + c4 * 4] = a;
        }
        // stage k half-tile 32x128
#pragma unroll
        for (int u = 0; u < 2; ++u) {
            int idx = u * 512 + t;
            int row = idx >> 5, c4 = idx & 31;
            float4 a = *(const float4*)&kk[(size_t)(jrow0 + row) * 256 + h * 128 + c4 * 4];
            *(float4*)&kbuf[row * QSTR + c4 * 4] = a;
        }
        __syncthreads();

#pragma unroll 1   // keep ds_read flight bounded; loop-carried state = s[4]
        for (int c0 = 0; c0 < 128; c0 += 8) {
            float4 qa = *(const float4*)&qbuf[l * QSTR + c0];
            float4 qb = *(const float4*)&qbuf[l * QSTR + c0 + 4];
#pragma unroll
            for (int jj = 0; jj < 4; ++jj) {
                float4 ka = *(const float4*)&kbuf[(j0 + jj) * QSTR + c0];      // broadcast
                float4 kb = *(const float4*)&kbuf[(j0 + jj) * QSTR + c0 + 4];  // broadcast
                s[jj] += fabsf(qa.x + ka.x);
                s[jj] += fabsf(qa.y + ka.y);
                s[jj] += fabsf(qa.z + ka.z);
                s[jj] += fabsf(qa.w + ka.w);
                s[jj] += fabsf(qb.x + kb.x);
                s[jj] += fabsf(qb.y + kb.y);
                s[jj] += fabsf(qb.z + kb.z);
                s[jj] += fabsf(qb.w + kb.w);
            }
        }
        __syncthreads();   // before restaging
    }

    // score' = 0.5*(Sabs + Ks_j)  (Ks via 4 precomputed partials, wave-uniform)
    const int jbase = jrow0 + j0;
    float sc[4];
#pragma unroll
    for (int jj = 0; jj < 4; ++jj) {
        float ks = Ksp[jbase + jj] + Ksp[1024 + jbase + jj]
                 + Ksp[2048 + jbase + jj] + Ksp[3072 + jbase + jj];
        sc[jj] = 0.5f * (s[jj] + ks);
        sL[j0 + jj][l] = sc[jj];
    }

    // stage v 32x256 into qbuf (q dead after score; barrier below publishes both)
#pragma unroll
    for (int u = 0; u < 4; ++u) {
        int idx = u * 512 + t;
        int row = idx >> 6, c4 = idx & 63;
        float4 a = *(const float4*)&vv[(size_t)(jrow0 + row) * 256 + c4 * 4];
        *(float4*)&qbuf[row * VSTR + c4 * 4] = a;
    }
    __syncthreads();

    float m = -1e30f;
#pragma unroll 8
    for (int j = 0; j < 32; ++j) m = fmaxf(m, sL[j][l]);
#pragma unroll
    for (int jj = 0; jj < 4; ++jj)
        pl[j0 + jj][l] = __expf(sc[jj] - m);
    __syncthreads();

    if (w == 0) {
        float lsum = 0.f;
#pragma unroll 8
        for (int j = 0; j < 32; ++j) lsum += pl[j][l];
        *(float2*)&ml[((size_t)(irow0 + l) * 16 + js) * 2] = make_float2(m, lsum);
    }

    // PV in TWO passes of 16 c each (acc[16] keeps pressure low).
    // Wave w owns c-slice [32w,32w+32); pass p covers [32w+16p, 32w+16p+16).
#pragma unroll 1
    for (int p = 0; p < 2; ++p) {
        const int cb = w * 32 + p * 16;
        float acc[16];
#pragma unroll
        for (int i = 0; i < 16; ++i) acc[i] = 0.f;
#pragma unroll 1
        for (int j = 0; j < 32; ++j) {
            float pj = pl[j][l];
#pragma unroll
            for (int c4 = 0; c4 < 4; ++c4) {
                float4 vv4 = *(const float4*)&qbuf[j * VSTR + cb + c4 * 4];  // broadcast
                acc[c4 * 4 + 0] += pj * vv4.x;
                acc[c4 * 4 + 1] += pj * vv4.y;
                acc[c4 * 4 + 2] += pj * vv4.z;
                acc[c4 * 4 + 3] += pj * vv4.w;
            }
        }
        float* pb = pacc + (((size_t)it * 16 + js) * 256 + cb) * 64 + l;
#pragma unroll
        for (int cc = 0; cc < 16; ++cc) pb[(size_t)cc * 64] = acc[cc];
    }
}

// ---------------- Kernel 3: combine split-j partials -> O^T [256][1024] ----------------
__global__ __launch_bounds__(256) void combine(
    const float* __restrict__ pacc, const float* __restrict__ ml, float* __restrict__ OT)
{
    const int it = blockIdx.x;   // 0..15
    const int cs = blockIdx.y;   // 0..15 (16-c slice)
    const int t  = threadIdx.x;
    const int il = t & 63, cq = t >> 6;      // cq 0..3
    const int row = it * 64 + il;
    const int c0  = cs * 16 + cq * 4;

    float mv[16], lv[16], M = -1e30f;
#pragma unroll
    for (int s = 0; s < 16; ++s) {
        float2 e = *(const float2*)&ml[((size_t)row * 16 + s) * 2];
        mv[s] = e.x; lv[s] = e.y; M = fmaxf(M, e.x);
    }
    float L = 0.f;
    float o[4] = {0.f, 0.f, 0.f, 0.f};
#pragma unroll
    for (int s = 0; s < 16; ++s) {
        float wgt = __expf(mv[s] - M);
        L += wgt * lv[s];
        const float* pb = pacc + (((size_t)it * 16 + s) * 256 + c0) * 64 + il;
#pragma unroll
        for (int i = 0; i < 4; ++i) o[i] += wgt * pb[(size_t)i * 64];
    }
    float inv = 1.f / L;
#pragma unroll
    for (int i = 0; i < 4; ++i)
        OT[(size_t)(c0 + i) * 1024 + row] = o[i] * inv;
}

// ---------------- Kernel 4: final projection + bias (reads O^T) ----------------
__global__ __launch_bounds__(256, 2) void gemm_bias(
    const float* __restrict__ OT, const float* __restrict__ W,
    const float* __restrict__ bias, float* __restrict__ out)
{
    const int row0 = blockIdx.x * 32;
    const int d0   = blockIdx.y * 64;

    __shared__ __attribute__((aligned(16))) float AT[32][36];
    __shared__ __attribute__((aligned(16))) float WT[32][68];

    const int tid = threadIdx.x;
    const int ty = tid >> 4, tx = tid & 15;

    float acc[2][4] = {};

    for (int c0 = 0; c0 < 256; c0 += 32) {
        {
            int cc = tid >> 3, r = (tid & 7) * 4;
            float4 a = *(const float4*)&OT[(size_t)(c0 + cc) * 1024 + row0 + r];
            *(float4*)&AT[cc][r] = a;
        }
        {
            int d  = tid >> 2;
            int cq = (tid & 3) * 8;
            float4 w0 = *(const float4*)&W[(size_t)(d0 + d) * 256 + c0 + cq];
            float4 w1 = *(const float4*)&W[(size_t)(d0 + d) * 256 + c0 + cq + 4];
            WT[cq + 0][d] = w0.x; WT[cq + 1][d] = w0.y;
            WT[cq + 2][d] = w0.z; WT[cq + 3][d] = w0.w;
            WT[cq + 4][d] = w1.x; WT[cq + 5][d] = w1.y;
            WT[cq + 6][d] = w1.z; WT[cq + 7][d] = w1.w;
        }
        __syncthreads();
#pragma unroll
        for (int c = 0; c < 32; ++c) {
            float2 a  = *(const float2*)&AT[c][ty * 2];
            float4 w4 = *(const float4*)&WT[c][tx * 4];
            acc[0][0] += a.x * w4.x; acc[0][1] += a.x * w4.y;
            acc[0][2] += a.x * w4.z; acc[0][3] += a.x * w4.w;
            acc[1][0] += a.y * w4.x; acc[1][1] += a.y * w4.y;
            acc[1][2] += a.y * w4.z; acc[1][3] += a.y * w4.w;
        }
        __syncthreads();
    }
    float4 bb = *(const float4*)&bias[d0 + tx * 4];
#pragma unroll
    for (int rr = 0; rr < 2; ++rr) {
        float4 o = make_float4(acc[rr][0] + bb.x, acc[rr][1] + bb.y,
                               acc[rr][2] + bb.z, acc[rr][3] + bb.w);
        *(float4*)&out[(size_t)(row0 + ty * 2 + rr) * 256 + d0 + tx * 4] = o;
    }
}

extern "C" void kernel_launch(void* const* d_in, const int* in_sizes, int n_in,
                              void* d_out, int out_size, void* d_ws, size_t ws_size,
                              hipStream_t stream) {
    const float* x  = (const float*)d_in[0];
    const float* Wq = (const float*)d_in[1];
    const float* Wk = (const float*)d_in[2];
    const float* Wv = (const float*)d_in[3];
    const float* Wp = (const float*)d_in[4];
    const float* bp = (const float*)d_in[5];
    float* out = (float*)d_out;
    (void)ws_size; (void)in_sizes; (void)n_in; (void)out_size;

    float* ws = (float*)d_ws;
    const size_t BNC = (size_t)2 * 512 * 256;              // 262144
    float4* qt4 = (float4*)ws;                             // [64 c4][1024] = 1 MB
    float* k    = ws + BNC;
    float* v    = k + BNC;
    float* OT   = v + BNC;                                 // [256][1024]
    float* Ksp  = OT + BNC;                                // [4][1024]
    float* pacc = Ksp + 4 * 1024;                          // [16][16][256][64] = 16.8 MB
    float* mlb  = pacc + (size_t)16 * 16 * 256 * 64;       // [1024][16][2]

    gemm_qkv<<<dim3(32, 4, 3), 256, 0, stream>>>(x, Wq, Wk, Wv, qt4, k, v, Ksp);
    attn_partial<<<dim3(16, 16), 512, 0, stream>>>(qt4, k, v, Ksp, pacc, mlb);
    combine<<<dim3(16, 16), 256, 0, stream>>>(pacc, mlb, OT);
    gemm_bias<<<dim3(32, 4), 256, 0, stream>>>(OT, Wp, bp, out);
}